// Round 1
// baseline (3223.106 us; speedup 1.0000x reference)
//
#include <hip/hip_runtime.h>
#include <hip/hip_bf16.h>
#include <math.h>

#define B 256
#define S 64
#define E 256
#define H 512
#define G4 2048   // 4*H gate columns, interleaved c = 4*u + g, g: 0=i,1=f,2=g,3=o
#define NC 32000

// ---------------------------------------------------------------------------
// zero-init state block (ws is poisoned 0xAA before every call)
__global__ __launch_bounds__(256) void k_zero(float4* __restrict__ p, int n4) {
    int i = blockIdx.x * 256 + threadIdx.x;
    if (i < n4) p[i] = float4{0.f, 0.f, 0.f, 0.f};
}

// ---------------------------------------------------------------------------
// embedding gather, time-major: emb[t][b][e] = C[X[b][t]][e]
__global__ __launch_bounds__(256) void k_emb(const int* __restrict__ X,
                                             const float* __restrict__ C,
                                             float* __restrict__ emb) {
    int i  = blockIdx.x * 256 + threadIdx.x;   // over S*B*E/4 = 1048576 float4
    int e4 = i & 63;                           // 64 float4 per row of E=256
    int tb = i >> 6;                           // t*B + b
    int t  = tb >> 8;
    int b  = tb & 255;
    int tok = X[b * S + t];
    float4 v = *(const float4*)(C + (size_t)tok * E + e4 * 4);
    *(float4*)(emb + (size_t)tb * E + e4 * 4) = v;
}

// ---------------------------------------------------------------------------
// interleave-transpose 4 gate matrices [H][K] -> outT [K][G4], outT[k][4u+g]=Wg[u][k]
__global__ __launch_bounds__(256) void k_interleave(const float* __restrict__ W0,
                                                    const float* __restrict__ W1,
                                                    const float* __restrict__ W2,
                                                    const float* __restrict__ W3,
                                                    int K, float* __restrict__ outT) {
    __shared__ float TT[64][65];   // [k_local][c_local]
    int u0 = blockIdx.x * 16;
    int k0 = blockIdx.y * 64;
    int tx = threadIdx.x & 15, ty = threadIdx.x >> 4;
    const float* Ws[4] = {W0, W1, W2, W3};
#pragma unroll
    for (int g = 0; g < 4; ++g) {
        float4 v = *(const float4*)(Ws[g] + (size_t)(u0 + ty) * K + k0 + tx * 4);
        TT[tx * 4 + 0][ty * 4 + g] = v.x;
        TT[tx * 4 + 1][ty * 4 + g] = v.y;
        TT[tx * 4 + 2][ty * 4 + g] = v.z;
        TT[tx * 4 + 3][ty * 4 + g] = v.w;
    }
    __syncthreads();
#pragma unroll
    for (int i = 0; i < 4; ++i) {
        int kk = ty + i * 16;
        float4 o;
        o.x = TT[kk][tx * 4 + 0];
        o.y = TT[kk][tx * 4 + 1];
        o.z = TT[kk][tx * 4 + 2];
        o.w = TT[kk][tx * 4 + 3];
        *(float4*)(outT + (size_t)(k0 + kk) * G4 + u0 * 4 + tx * 4) = o;
    }
}

// ---------------------------------------------------------------------------
// combined layer-1 x-path weights: WcT[k][c] = sum_e Wi_g[u][e] * W[e][k]
__global__ __launch_bounds__(256) void k_combined(const float* __restrict__ Wi0,
                                                  const float* __restrict__ Wi1,
                                                  const float* __restrict__ Wi2,
                                                  const float* __restrict__ Wi3,
                                                  const float* __restrict__ W,
                                                  float* __restrict__ WcT) {
    __shared__ float WiLS[64][65];  // [c_local][e_local]
    __shared__ float WLS[64][64];   // [e_local][k_local]
    int c0 = blockIdx.x * 64;
    int u0 = c0 >> 2;
    int k0 = blockIdx.y * 64;
    int tx = threadIdx.x & 15, ty = threadIdx.x >> 4;
    const float* Ws[4] = {Wi0, Wi1, Wi2, Wi3};
    float acc[4][4] = {};           // [kj][ci]
    for (int e0 = 0; e0 < E; e0 += 64) {
#pragma unroll
        for (int g = 0; g < 4; ++g) {
            float4 v = *(const float4*)(Ws[g] + (size_t)(u0 + ty) * E + e0 + tx * 4);
            WiLS[ty * 4 + g][tx * 4 + 0] = v.x;
            WiLS[ty * 4 + g][tx * 4 + 1] = v.y;
            WiLS[ty * 4 + g][tx * 4 + 2] = v.z;
            WiLS[ty * 4 + g][tx * 4 + 3] = v.w;
        }
#pragma unroll
        for (int i = 0; i < 4; ++i) {
            float4 v = *(const float4*)(W + (size_t)(e0 + ty + i * 16) * H + k0 + tx * 4);
            *(float4*)&WLS[ty + i * 16][tx * 4] = v;
        }
        __syncthreads();
#pragma unroll
        for (int el = 0; el < 64; ++el) {
            float wv[4], iv[4];
#pragma unroll
            for (int j = 0; j < 4; ++j) {
                wv[j] = WLS[el][ty * 4 + j];
                iv[j] = WiLS[tx * 4 + j][el];
            }
#pragma unroll
            for (int kj = 0; kj < 4; ++kj)
#pragma unroll
                for (int ci = 0; ci < 4; ++ci) acc[kj][ci] += wv[kj] * iv[ci];
        }
        __syncthreads();
    }
#pragma unroll
    for (int kj = 0; kj < 4; ++kj) {
        float4 o = {acc[kj][0], acc[kj][1], acc[kj][2], acc[kj][3]};
        *(float4*)(WcT + (size_t)(k0 + ty * 4 + kj) * G4 + c0 + tx * 4) = o;
    }
}

// ---------------------------------------------------------------------------
// biases: bias0[c] = b_g[u];  bias1[c] = b_g[u] + sum_e Wi_g[u][e]*b[e] (via WxT)
__global__ __launch_bounds__(256) void k_bias(const float* __restrict__ WxT,
                                              const float* __restrict__ bi,
                                              const float* __restrict__ bf,
                                              const float* __restrict__ bg,
                                              const float* __restrict__ bo,
                                              const float* __restrict__ bvec,
                                              float* __restrict__ bias0,
                                              float* __restrict__ bias1) {
    int c = blockIdx.x * 256 + threadIdx.x;  // 2048
    int g = c & 3, u = c >> 2;
    const float* bp = (g == 0) ? bi : (g == 1) ? bf : (g == 2) ? bg : bo;
    float base = bp[u];
    float s = 0.f;
    for (int e = 0; e < E; ++e) s += WxT[(size_t)e * G4 + c] * bvec[e];
    bias0[c] = base;
    bias1[c] = base + s;
}

// ---------------------------------------------------------------------------
// one staggered phase: y==0 -> layer0 step p (p<S); y==1 -> layer1 step p-1 (p>=1)
// preact[b][c] = sum_k xin[b][k]*WxT[k][c] + sum_k hprev[b][k]*WhT[k][c] + bias[c]
__global__ __launch_bounds__(256) void k_phase(int p,
                                               const float* __restrict__ emb,
                                               const float* __restrict__ WxT,
                                               const float* __restrict__ WcT,
                                               const float* __restrict__ WhT,
                                               const float* __restrict__ bias0,
                                               const float* __restrict__ bias1,
                                               float* __restrict__ h0buf,
                                               float* __restrict__ h1buf,
                                               float* __restrict__ c0g,
                                               float* __restrict__ c1g) {
    const int layer = blockIdx.y;
    if (layer == 0 && p >= S) return;
    if (layer == 1 && p == 0) return;

    const float* xin;
    const float* WxTs;
    int Kx;
    const float* hprev;
    float* hout;
    float* cbuf;
    const float* bias;
    if (layer == 0) {
        xin   = emb + (size_t)p * B * E;
        WxTs  = WxT;
        Kx    = E;
        hprev = h0buf + (size_t)((p + 1) & 1) * B * H;
        hout  = h0buf + (size_t)(p & 1) * B * H;
        cbuf  = c0g;
        bias  = bias0;
    } else {
        int q = p - 1;
        xin   = h0buf + (size_t)(q & 1) * B * H;
        WxTs  = WcT;
        Kx    = H;
        hprev = h1buf + (size_t)((q + 1) & 1) * B * H;
        hout  = h1buf + (size_t)(q & 1) * B * H;
        cbuf  = c1g;
        bias  = bias1;
    }

    const int bt  = blockIdx.x & 3;    // 4 batch tiles of 64
    const int ut  = blockIdx.x >> 2;   // 32 unit tiles of 16 (=64 gate cols)
    const int tid = threadIdx.x;
    const int tx  = tid & 15;          // unit in tile
    const int ty  = tid >> 4;
    const int b0  = bt * 64;
    const int cb0 = ut * 64;

    __shared__ float ALS[64][65];
    __shared__ float BLS[64][64];

    float acc[4][4];
#pragma unroll
    for (int r = 0; r < 4; ++r)
#pragma unroll
        for (int g = 0; g < 4; ++g) acc[r][g] = 0.f;

    for (int seg = 0; seg < 2; ++seg) {
        const float* A  = seg ? hprev : xin;
        const float* Bw = seg ? WhT : WxTs;
        const int K     = seg ? H : Kx;
        for (int k0 = 0; k0 < K; k0 += 64) {
#pragma unroll
            for (int i = 0; i < 4; ++i) {
                int row  = ty + i * 16;
                float4 v = *(const float4*)(A + (size_t)(b0 + row) * K + k0 + tx * 4);
                ALS[row][tx * 4 + 0] = v.x;
                ALS[row][tx * 4 + 1] = v.y;
                ALS[row][tx * 4 + 2] = v.z;
                ALS[row][tx * 4 + 3] = v.w;
            }
#pragma unroll
            for (int i = 0; i < 4; ++i) {
                int row  = ty + i * 16;
                float4 v = *(const float4*)(Bw + (size_t)(k0 + row) * G4 + cb0 + tx * 4);
                *(float4*)&BLS[row][tx * 4] = v;
            }
            __syncthreads();
#pragma unroll
            for (int kk = 0; kk < 64; ++kk) {
                float4 bv = *(const float4*)&BLS[kk][tx * 4];
                float a0  = ALS[ty * 4 + 0][kk];
                float a1  = ALS[ty * 4 + 1][kk];
                float a2  = ALS[ty * 4 + 2][kk];
                float a3  = ALS[ty * 4 + 3][kk];
                acc[0][0] += a0 * bv.x; acc[0][1] += a0 * bv.y; acc[0][2] += a0 * bv.z; acc[0][3] += a0 * bv.w;
                acc[1][0] += a1 * bv.x; acc[1][1] += a1 * bv.y; acc[1][2] += a1 * bv.z; acc[1][3] += a1 * bv.w;
                acc[2][0] += a2 * bv.x; acc[2][1] += a2 * bv.y; acc[2][2] += a2 * bv.z; acc[2][3] += a2 * bv.w;
                acc[3][0] += a3 * bv.x; acc[3][1] += a3 * bv.y; acc[3][2] += a3 * bv.z; acc[3][3] += a3 * bv.w;
            }
            __syncthreads();
        }
    }

    // elementwise LSTM update; thread owns all 4 gates of unit u for 4 batch rows
    const int u = ut * 16 + tx;
    float4 bb   = *(const float4*)(bias + cb0 + tx * 4);
#pragma unroll
    for (int r = 0; r < 4; ++r) {
        int b    = b0 + ty * 4 + r;
        float pi = acc[r][0] + bb.x;
        float pf = acc[r][1] + bb.y;
        float pg = acc[r][2] + bb.z;
        float po = acc[r][3] + bb.w;
        float i_ = 1.f / (1.f + expf(-pi));
        float f_ = 1.f / (1.f + expf(-pf));
        float g_ = tanhf(pg);
        float o_ = 1.f / (1.f + expf(-po));
        size_t idx = (size_t)b * H + u;
        float cn = f_ * cbuf[idx] + i_ * g_;
        float hn = o_ * tanhf(cn);
        cbuf[idx] = cn;
        hout[idx] = hn;
    }
}

// ---------------------------------------------------------------------------
// classifier: out[b][n] = sum_k h[b][k]*Wf[n][k] + bfin[n]
// tile 64b x 128n, K-chunks of 64 with in-LDS transpose of Wf
__global__ __launch_bounds__(256) void k_classifier(const float* __restrict__ h,
                                                    const float* __restrict__ Wf,
                                                    const float* __restrict__ bfin,
                                                    float* __restrict__ out) {
    const int n0 = blockIdx.x * 128;
    const int b0 = blockIdx.y * 64;
    const int tid = threadIdx.x;
    const int tx = tid & 31;   // 4 n each -> 128
    const int ty = tid >> 5;   // 8 rows each -> 64

    __shared__ float ALS[64][65];
    __shared__ float BT[64][129];   // [k_local][n_local]

    float acc[8][4] = {};

    for (int k0 = 0; k0 < H; k0 += 64) {
        {   // stage h tile 64x64
            int lx = tid & 15, ly = tid >> 4;
#pragma unroll
            for (int i = 0; i < 4; ++i) {
                int row  = ly + i * 16;
                float4 v = *(const float4*)(h + (size_t)(b0 + row) * H + k0 + lx * 4);
                ALS[row][lx * 4 + 0] = v.x;
                ALS[row][lx * 4 + 1] = v.y;
                ALS[row][lx * 4 + 2] = v.z;
                ALS[row][lx * 4 + 3] = v.w;
            }
        }
        {   // stage Wf tile 128n x 64k, transposed into BT[k][n]
            int lx = tid & 15, ly = tid >> 4;
#pragma unroll
            for (int i = 0; i < 8; ++i) {
                int row  = ly + i * 16;   // n_local 0..127
                float4 v = *(const float4*)(Wf + (size_t)(n0 + row) * H + k0 + lx * 4);
                BT[lx * 4 + 0][row] = v.x;
                BT[lx * 4 + 1][row] = v.y;
                BT[lx * 4 + 2][row] = v.z;
                BT[lx * 4 + 3][row] = v.w;
            }
        }
        __syncthreads();
#pragma unroll
        for (int kk = 0; kk < 64; ++kk) {
            float bv0 = BT[kk][tx * 4 + 0];
            float bv1 = BT[kk][tx * 4 + 1];
            float bv2 = BT[kk][tx * 4 + 2];
            float bv3 = BT[kk][tx * 4 + 3];
#pragma unroll
            for (int r = 0; r < 8; ++r) {
                float a = ALS[ty * 8 + r][kk];
                acc[r][0] += a * bv0;
                acc[r][1] += a * bv1;
                acc[r][2] += a * bv2;
                acc[r][3] += a * bv3;
            }
        }
        __syncthreads();
    }

    float4 bb = *(const float4*)(bfin + n0 + tx * 4);
#pragma unroll
    for (int r = 0; r < 8; ++r) {
        float4 o = {acc[r][0] + bb.x, acc[r][1] + bb.y, acc[r][2] + bb.z, acc[r][3] + bb.w};
        *(float4*)(out + (size_t)(b0 + ty * 8 + r) * NC + n0 + tx * 4) = o;
    }
}

// ---------------------------------------------------------------------------
extern "C" void kernel_launch(void* const* d_in, const int* in_sizes, int n_in,
                              void* d_out, int out_size, void* d_ws, size_t ws_size,
                              hipStream_t stream) {
    const int*   X    = (const int*)d_in[0];
    const float* C    = (const float*)d_in[1];
    const float* Wii  = (const float*)d_in[2];
    const float* Whi  = (const float*)d_in[3];
    const float* bi   = (const float*)d_in[4];
    const float* Wif  = (const float*)d_in[5];
    const float* Whf  = (const float*)d_in[6];
    const float* bf   = (const float*)d_in[7];
    const float* Wig  = (const float*)d_in[8];
    const float* Whg  = (const float*)d_in[9];
    const float* bg   = (const float*)d_in[10];
    const float* Wio  = (const float*)d_in[11];
    const float* Who  = (const float*)d_in[12];
    const float* bo   = (const float*)d_in[13];
    const float* W    = (const float*)d_in[14];
    const float* bvec = (const float*)d_in[15];
    const float* Wf   = (const float*)d_in[16];
    const float* bfin = (const float*)d_in[17];
    float* out = (float*)d_out;
    float* ws  = (float*)d_ws;

    // ws layout (floats)
    float* emb    = ws;                  // 64*256*256      = 4,194,304
    float* WhT    = ws + 4194304;        // 512*2048        = 1,048,576
    float* WxT    = ws + 5242880;        // 256*2048        =   524,288
    float* WcT    = ws + 5767168;        // 512*2048        = 1,048,576
    float* bias0  = ws + 6815744;        // 2048
    float* bias1  = ws + 6817792;        // 2048
    float* states = ws + 6819840;        // 6*B*H = 786,432
    float* h0b = states;
    float* h1b = states + 2 * B * H;
    float* c0g = states + 4 * B * H;
    float* c1g = states + 5 * B * H;
    // total 7,606,272 floats = 30.4 MB

    k_zero<<<dim3(768), dim3(256), 0, stream>>>((float4*)states, 6 * B * H / 4);
    k_emb<<<dim3(4096), dim3(256), 0, stream>>>(X, C, emb);
    k_interleave<<<dim3(32, 8), dim3(256), 0, stream>>>(Whi, Whf, Whg, Who, H, WhT);
    k_interleave<<<dim3(32, 4), dim3(256), 0, stream>>>(Wii, Wif, Wig, Wio, E, WxT);
    k_combined<<<dim3(32, 8), dim3(256), 0, stream>>>(Wii, Wif, Wig, Wio, W, WcT);
    k_bias<<<dim3(8), dim3(256), 0, stream>>>(WxT, bi, bf, bg, bo, bvec, bias0, bias1);

    for (int p = 0; p <= S; ++p)
        k_phase<<<dim3(128, 2), dim3(256), 0, stream>>>(p, emb, WxT, WcT, WhT, bias0,
                                                        bias1, h0b, h1b, c0g, c1g);

    // final h1 lives in h1buf parity (S-1)&1 = 1
    k_classifier<<<dim3(250, 4), dim3(256), 0, stream>>>(h1b + B * H, Wf, bfin, out);
}

// Round 8
// 1725.849 us; speedup vs baseline: 1.8675x; 1.8675x over previous
//
#include <hip/hip_runtime.h>
#include <hip/hip_bf16.h>
#include <math.h>

#define B 256
#define S 64
#define E 256
#define H 512
#define NC 32000

typedef __attribute__((ext_vector_type(8))) short short8;   // 8 bf16 = 4 VGPR
typedef __attribute__((ext_vector_type(4))) float f32x4;

__device__ inline short f2bf(float v) {
    __hip_bfloat16 h = __float2bfloat16(v);
    return *reinterpret_cast<short*>(&h);
}
__device__ inline float bf2f(short s) {
    __hip_bfloat16 h;
    *reinterpret_cast<short*>(&h) = s;
    return __bfloat162float(h);
}

// ---------------------------------------------------------------------------
__global__ __launch_bounds__(256) void k_zero(float4* __restrict__ p, int n4) {
    int i = blockIdx.x * 256 + threadIdx.x;
    if (i < n4) p[i] = float4{0.f, 0.f, 0.f, 0.f};
}

// ---------------------------------------------------------------------------
// gate-blocked transpose: outT[k][g*512+u] = Wg[u][k]   (Wg is [H][K])
__global__ __launch_bounds__(256) void k_trans(const float* __restrict__ W0,
                                               const float* __restrict__ W1,
                                               const float* __restrict__ W2,
                                               const float* __restrict__ W3,
                                               int K, float* __restrict__ outT) {
    __shared__ float TT[64][65];   // [k_local][u_local]
    const int u0 = blockIdx.x * 64;
    const int k0 = blockIdx.y * 64;
    const int g  = blockIdx.z;
    const float* Wg = (g == 0) ? W0 : (g == 1) ? W1 : (g == 2) ? W2 : W3;
    const int tx = threadIdx.x & 15, ty = threadIdx.x >> 4;
#pragma unroll
    for (int i = 0; i < 4; ++i) {
        float4 v = *(const float4*)(Wg + (size_t)(u0 + ty + i * 16) * K + k0 + tx * 4);
        TT[tx * 4 + 0][ty + i * 16] = v.x;
        TT[tx * 4 + 1][ty + i * 16] = v.y;
        TT[tx * 4 + 2][ty + i * 16] = v.z;
        TT[tx * 4 + 3][ty + i * 16] = v.w;
    }
    __syncthreads();
#pragma unroll
    for (int i = 0; i < 4; ++i) {
        int kl = ty + i * 16;
        float4 o = {TT[kl][tx * 4 + 0], TT[kl][tx * 4 + 1], TT[kl][tx * 4 + 2], TT[kl][tx * 4 + 3]};
        *(float4*)(outT + (size_t)(k0 + kl) * 2048 + g * 512 + u0 + tx * 4) = o;
    }
}

// ---------------------------------------------------------------------------
// combined layer-1 x-path: WcT[k][g*512+u] = sum_e Wi_g[u][e] * W[e][k]
__global__ __launch_bounds__(256) void k_comb(const float* __restrict__ Wi0,
                                              const float* __restrict__ Wi1,
                                              const float* __restrict__ Wi2,
                                              const float* __restrict__ Wi3,
                                              const float* __restrict__ W,
                                              float* __restrict__ WcT) {
    __shared__ float WiS[64][65];   // [u_local][e_local]
    __shared__ float WS[64][65];    // [e_local][k_local]
    const int g  = blockIdx.x >> 3;
    const int u0 = (blockIdx.x & 7) * 64;
    const int k0 = blockIdx.y * 64;
    const float* Wi = (g == 0) ? Wi0 : (g == 1) ? Wi1 : (g == 2) ? Wi2 : Wi3;
    const int tx = threadIdx.x & 15, ty = threadIdx.x >> 4;
    float acc[4][4] = {};   // [ui][kj]
    for (int e0 = 0; e0 < E; e0 += 64) {
#pragma unroll
        for (int i = 0; i < 4; ++i) {
            float4 v = *(const float4*)(Wi + (size_t)(u0 + ty + i * 16) * E + e0 + tx * 4);
            *(float4*)&WiS[ty + i * 16][tx * 4] = v;
        }
#pragma unroll
        for (int i = 0; i < 4; ++i) {
            float4 v = *(const float4*)(W + (size_t)(e0 + ty + i * 16) * H + k0 + tx * 4);
            *(float4*)&WS[ty + i * 16][tx * 4] = v;
        }
        __syncthreads();
#pragma unroll
        for (int el = 0; el < 64; ++el) {
            float uv[4], kv[4];
#pragma unroll
            for (int j = 0; j < 4; ++j) { uv[j] = WiS[ty * 4 + j][el]; kv[j] = WS[el][tx * 4 + j]; }
#pragma unroll
            for (int i2 = 0; i2 < 4; ++i2)
#pragma unroll
                for (int j = 0; j < 4; ++j) acc[i2][j] += uv[i2] * kv[j];
        }
        __syncthreads();
    }
#pragma unroll
    for (int j = 0; j < 4; ++j) {
        float4 o = {acc[0][j], acc[1][j], acc[2][j], acc[3][j]};
        *(float4*)(WcT + (size_t)(k0 + tx * 4 + j) * 2048 + g * 512 + u0 + ty * 4) = o;
    }
}

// ---------------------------------------------------------------------------
// biases (gate-blocked): bias0[g*512+u]=b_g[u]; bias1 += sum_e Wi_g[u][e]*b[e]
__global__ __launch_bounds__(256) void k_bias(const float* __restrict__ WxT,
                                              const float* __restrict__ bi,
                                              const float* __restrict__ bf_,
                                              const float* __restrict__ bg_,
                                              const float* __restrict__ bo_,
                                              const float* __restrict__ bvec,
                                              float* __restrict__ bias0,
                                              float* __restrict__ bias1) {
    int c = blockIdx.x * 256 + threadIdx.x;  // 2048
    int g = c >> 9, u = c & 511;
    const float* bp = (g == 0) ? bi : (g == 1) ? bf_ : (g == 2) ? bg_ : bo_;
    float basev = bp[u];
    float s = 0.f;
    for (int e = 0; e < E; ++e) s += WxT[(size_t)e * 2048 + c] * bvec[e];
    bias0[c] = basev;
    bias1[c] = basev + s;
}

// ---------------------------------------------------------------------------
// pack fp32 [K][2048] into MFMA b-operand fragments, hi/lo bf16 interleaved:
// out[((kb*128 + nb)*2 + h)*512 + lane*8 + j] ;  k=kb*32+(lane>>4)*8+j ; n=nb*16+(lane&15)
__global__ __launch_bounds__(256) void k_pack(const float* __restrict__ Wt,
                                              short* __restrict__ outp) {
    int idx = blockIdx.x * 256 + threadIdx.x;  // K*2048 elements
    int k = idx >> 11, n = idx & 2047;
    float v = Wt[(size_t)k * 2048 + n];
    short hi = f2bf(v);
    short lo = f2bf(v - bf2f(hi));
    int kb = k >> 5, ks = (k >> 3) & 3, j = k & 7;
    int nb = n >> 4, nl = n & 15;
    int lane = ks * 16 + nl;
    size_t base = (((size_t)kb * 128 + nb) * 2) * 512 + (size_t)lane * 8 + j;
    outp[base] = hi;
    outp[base + 512] = lo;
}

// ---------------------------------------------------------------------------
// 16-step K=512 GEMM sub-loop: A (bf16 hi/lo rows) x packed B, bf16x3 split
__device__ __forceinline__ void gemm_h(const short* __restrict__ aH,
                                       const short* __restrict__ aL,
                                       const short* __restrict__ Bp,
                                       int ubG, int lane, int ks, f32x4 acc[4]) {
#pragma unroll 4
    for (int kb = 0; kb < 16; ++kb) {
        int ko = kb * 32 + ks * 8;
        short8 ahi = *(const short8*)(aH + ko);
        short8 alo = *(const short8*)(aL + ko);
#pragma unroll
        for (int g = 0; g < 4; ++g) {
            const short* bp = Bp + ((((size_t)kb * 4 + g) * 32) + ubG) * 1024 + (size_t)lane * 8;
            short8 bhi = *(const short8*)bp;
            short8 blo = *(const short8*)(bp + 512);
            acc[g] = __builtin_amdgcn_mfma_f32_16x16x32_bf16(ahi, bhi, acc[g], 0, 0, 0);
            acc[g] = __builtin_amdgcn_mfma_f32_16x16x32_bf16(alo, bhi, acc[g], 0, 0, 0);
            acc[g] = __builtin_amdgcn_mfma_f32_16x16x32_bf16(ahi, blo, acc[g], 0, 0, 0);
        }
    }
}

// ---------------------------------------------------------------------------
// staggered phase: panel0 = layer0 step p (p<S); panel1 = layer1 step p-1 (p>=1)
// grid (128,2): blockIdx.x -> 4 m-supertiles x 32 u-blocks; 4 waves = 4 m-subtiles
__global__ __launch_bounds__(256) void k_phase(int p, const int* __restrict__ X,
        const float* __restrict__ C,
        const short* __restrict__ WxP, const short* __restrict__ WcP,
        const short* __restrict__ WhP,
        const float* __restrict__ bias0g, const float* __restrict__ bias1g,
        short* __restrict__ h0H, short* __restrict__ h0L,
        short* __restrict__ h1H, short* __restrict__ h1L,
        float* __restrict__ c0, float* __restrict__ c1) {
    const int panel = blockIdx.y;
    if (panel == 0 && p >= S) return;
    if (panel == 1 && p == 0) return;
    const int tid  = threadIdx.x;
    const int wave = tid >> 6, lane = tid & 63;
    const int lrow = lane & 15, ks = lane >> 4;
    const int msup = blockIdx.x & 3;      // 4 m-supertiles of 64 rows
    const int ubG  = blockIdx.x >> 2;     // 32 u-blocks of 16 units
    const int row  = msup * 64 + wave * 16 + lrow;   // A-row this lane loads
    const int u    = ubG * 16 + lrow;

    f32x4 acc[4];
#pragma unroll
    for (int g = 0; g < 4; ++g) acc[g] = (f32x4){0.f, 0.f, 0.f, 0.f};

    if (panel == 0) {
        // x-part: embedding gathered from C, split to bf16 hi/lo in-register
        const int tok = X[row * S + p];
        const float* crow = C + (size_t)tok * E;
#pragma unroll 2
        for (int kb = 0; kb < 8; ++kb) {
            int ko = kb * 32 + ks * 8;
            float4 v0 = *(const float4*)(crow + ko);
            float4 v1 = *(const float4*)(crow + ko + 4);
            float v[8] = {v0.x, v0.y, v0.z, v0.w, v1.x, v1.y, v1.z, v1.w};
            short8 ahi, alo;
#pragma unroll
            for (int j = 0; j < 8; ++j) {
                short hj = f2bf(v[j]);
                ahi[j] = hj;
                alo[j] = f2bf(v[j] - bf2f(hj));
            }
#pragma unroll
            for (int g = 0; g < 4; ++g) {
                const short* bp = WxP + ((((size_t)kb * 4 + g) * 32) + ubG) * 1024 + (size_t)lane * 8;
                short8 bhi = *(const short8*)bp;
                short8 blo = *(const short8*)(bp + 512);
                acc[g] = __builtin_amdgcn_mfma_f32_16x16x32_bf16(ahi, bhi, acc[g], 0, 0, 0);
                acc[g] = __builtin_amdgcn_mfma_f32_16x16x32_bf16(alo, bhi, acc[g], 0, 0, 0);
                acc[g] = __builtin_amdgcn_mfma_f32_16x16x32_bf16(ahi, blo, acc[g], 0, 0, 0);
            }
        }
        // h-part: h0 parity (p+1)&1
        size_t off = (size_t)((p + 1) & 1) * B * H + (size_t)row * H;
        gemm_h(h0H + off, h0L + off, WhP, ubG, lane, ks, acc);
    } else {
        const int q = p - 1;
        size_t offx = (size_t)(q & 1) * B * H + (size_t)row * H;          // x = h0[q]
        gemm_h(h0H + offx, h0L + offx, WcP, ubG, lane, ks, acc);
        size_t offh = (size_t)((q + 1) & 1) * B * H + (size_t)row * H;    // h1[q-1]
        gemm_h(h1H + offh, h1L + offh, WhP, ubG, lane, ks, acc);
    }

    // epilogue: lane holds all 4 gate preacts for (b=rbase+r, u)
    short* dH; short* dL; float* cb;
    if (panel == 0) { size_t off = (size_t)(p & 1) * B * H; dH = h0H + off; dL = h0L + off; cb = c0; }
    else            { size_t off = (size_t)((p - 1) & 1) * B * H; dH = h1H + off; dL = h1L + off; cb = c1; }
    const float* bias = panel ? bias1g : bias0g;
    const float bI = bias[u], bF = bias[512 + u], bG = bias[1024 + u], bO = bias[1536 + u];
    const int rbase = msup * 64 + wave * 16 + ks * 4;
#pragma unroll
    for (int r = 0; r < 4; ++r) {
        size_t ix = (size_t)(rbase + r) * H + u;
        float pi = acc[0][r] + bI;
        float pf = acc[1][r] + bF;
        float pg = acc[2][r] + bG;
        float po = acc[3][r] + bO;
        float iv = 1.f / (1.f + expf(-pi));
        float fv = 1.f / (1.f + expf(-pf));
        float gv = tanhf(pg);
        float ov = 1.f / (1.f + expf(-po));
        float cn = fv * cb[ix] + iv * gv;
        float hn = ov * tanhf(cn);
        cb[ix] = cn;
        short hh = f2bf(hn);
        dH[ix] = hh;
        dL[ix] = f2bf(hn - bf2f(hh));
    }
}

// ---------------------------------------------------------------------------
// classifier: out[b][n] = h[b] . Wf[n] + bfin[n]; A split (exact), B bf16 (x2)
// grid 250, block 1024 (16 waves = all 256 rows); n0 = blk*128, wave n-slices of 16x8
__global__ __launch_bounds__(1024) void k_cls(const short* __restrict__ hH,
                                              const short* __restrict__ hL,
                                              const float* __restrict__ Wf,
                                              const float* __restrict__ bfin,
                                              float* __restrict__ out) {
    const int tid  = threadIdx.x;
    const int wave = tid >> 6, lane = tid & 63;
    const int lrow = lane & 15, ks = lane >> 4;
    const int n0 = blockIdx.x * 128;
    const int m0 = wave * 16;
    f32x4 acc[8];
#pragma unroll
    for (int nf = 0; nf < 8; ++nf) acc[nf] = (f32x4){0.f, 0.f, 0.f, 0.f};
    const short* aH = hH + (size_t)(m0 + lrow) * H;
    const short* aL = hL + (size_t)(m0 + lrow) * H;
#pragma unroll 2
    for (int kb = 0; kb < 16; ++kb) {
        int ko = kb * 32 + ks * 8;
        short8 ahi = *(const short8*)(aH + ko);
        short8 alo = *(const short8*)(aL + ko);
#pragma unroll
        for (int nf = 0; nf < 8; ++nf) {
            const float* wr = Wf + (size_t)(n0 + nf * 16 + lrow) * H + ko;
            float4 v0 = *(const float4*)wr;
            float4 v1 = *(const float4*)(wr + 4);
            short8 b;
            b[0] = f2bf(v0.x); b[1] = f2bf(v0.y); b[2] = f2bf(v0.z); b[3] = f2bf(v0.w);
            b[4] = f2bf(v1.x); b[5] = f2bf(v1.y); b[6] = f2bf(v1.z); b[7] = f2bf(v1.w);
            acc[nf] = __builtin_amdgcn_mfma_f32_16x16x32_bf16(ahi, b, acc[nf], 0, 0, 0);
            acc[nf] = __builtin_amdgcn_mfma_f32_16x16x32_bf16(alo, b, acc[nf], 0, 0, 0);
        }
    }
#pragma unroll
    for (int nf = 0; nf < 8; ++nf) {
        int n = n0 + nf * 16 + lrow;
        float bias = bfin[n];
#pragma unroll
        for (int r = 0; r < 4; ++r) {
            int brow = m0 + ks * 4 + r;
            out[(size_t)brow * NC + n] = acc[nf][r] + bias;
        }
    }
}

// ---------------------------------------------------------------------------
extern "C" void kernel_launch(void* const* d_in, const int* in_sizes, int n_in,
                              void* d_out, int out_size, void* d_ws, size_t ws_size,
                              hipStream_t stream) {
    const int*   X    = (const int*)d_in[0];
    const float* C    = (const float*)d_in[1];
    const float* Wii  = (const float*)d_in[2];
    const float* Whi  = (const float*)d_in[3];
    const float* bi   = (const float*)d_in[4];
    const float* Wif  = (const float*)d_in[5];
    const float* Whf  = (const float*)d_in[6];
    const float* bf   = (const float*)d_in[7];
    const float* Wig  = (const float*)d_in[8];
    const float* Whg  = (const float*)d_in[9];
    const float* bg   = (const float*)d_in[10];
    const float* Wio  = (const float*)d_in[11];
    const float* Who  = (const float*)d_in[12];
    const float* bo   = (const float*)d_in[13];
    const float* W    = (const float*)d_in[14];
    const float* bvec = (const float*)d_in[15];
    const float* Wf   = (const float*)d_in[16];
    const float* bfin = (const float*)d_in[17];
    float* out = (float*)d_out;
    char* base = (char*)d_ws;

    // ws layout (bytes), total ~24.1 MB
    float* WhT  = (float*)(base + 0);          // 512*2048*4 = 4,194,304
    float* WxT  = (float*)(base + 4194304);    // 256*2048*4 = 2,097,152
    float* WcT  = (float*)(base + 6291456);    // 4,194,304
    short* WhP  = (short*)(base + 10485760);   // 4,194,304
    short* WxP  = (short*)(base + 14680064);   // 2,097,152
    short* WcP  = (short*)(base + 16777216);   // 4,194,304
    float* bias0 = (float*)(base + 20971520);  // 8192
    float* bias1 = (float*)(base + 20979712);  // 8192
    short* h0H  = (short*)(base + 20987904);   // [2][256][512] bf16 = 524,288 each
    short* h0L  = (short*)(base + 21512192);
    short* h1H  = (short*)(base + 22036480);
    short* h1L  = (short*)(base + 22560768);
    float* c0   = (float*)(base + 23085056);   // 524,288
    float* c1   = (float*)(base + 23609344);   // 524,288

    // zero h-splits (both parities) + cell states: 6*524288 B = 196608 float4
    k_zero<<<768, 256, 0, stream>>>((float4*)(base + 20987904), 196608);

    k_trans<<<dim3(8, 8, 4), 256, 0, stream>>>(Whi, Whf, Whg, Who, H, WhT);
    k_trans<<<dim3(8, 4, 4), 256, 0, stream>>>(Wii, Wif, Wig, Wio, E, WxT);
    k_comb<<<dim3(32, 8), 256, 0, stream>>>(Wii, Wif, Wig, Wio, W, WcT);
    k_pack<<<4096, 256, 0, stream>>>(WhT, WhP);
    k_pack<<<2048, 256, 0, stream>>>(WxT, WxP);
    k_pack<<<4096, 256, 0, stream>>>(WcT, WcP);
    k_bias<<<8, 256, 0, stream>>>(WxT, bi, bf, bg, bo, bvec, bias0, bias1);

    for (int p = 0; p <= S; ++p)
        k_phase<<<dim3(128, 2), 256, 0, stream>>>(p, X, C, WxP, WcP, WhP, bias0, bias1,
                                                  h0H, h0L, h1H, h1L, c0, c1);

    // final h1 (t=63) is in parity 1
    k_cls<<<250, 1024, 0, stream>>>(h1H + (size_t)B * H, h1L + (size_t)B * H, Wf, bfin, out);
}

// Round 9
// 1621.038 us; speedup vs baseline: 1.9883x; 1.0647x over previous
//
#include <hip/hip_runtime.h>
#include <hip/hip_bf16.h>
#include <math.h>

#define B 256
#define S 64
#define E 256
#define H 512
#define NC 32000

typedef __attribute__((ext_vector_type(8))) short short8;   // 8 bf16 = 4 VGPR
typedef __attribute__((ext_vector_type(4))) float f32x4;

__device__ inline short f2bf(float v) {
    __hip_bfloat16 h = __float2bfloat16(v);
    return *reinterpret_cast<short*>(&h);
}
__device__ inline float bf2f(short s) {
    __hip_bfloat16 h;
    *reinterpret_cast<short*>(&h) = s;
    return __bfloat162float(h);
}

// ---------------------------------------------------------------------------
__global__ __launch_bounds__(256) void k_zero(float4* __restrict__ p, int n4) {
    int i = blockIdx.x * 256 + threadIdx.x;
    if (i < n4) p[i] = float4{0.f, 0.f, 0.f, 0.f};
}

// ---------------------------------------------------------------------------
// gate-blocked transpose: outT[k][g*512+u] = Wg[u][k]   (Wg is [H][K])
__global__ __launch_bounds__(256) void k_trans(const float* __restrict__ W0,
                                               const float* __restrict__ W1,
                                               const float* __restrict__ W2,
                                               const float* __restrict__ W3,
                                               int K, float* __restrict__ outT) {
    __shared__ float TT[64][65];   // [k_local][u_local]
    const int u0 = blockIdx.x * 64;
    const int k0 = blockIdx.y * 64;
    const int g  = blockIdx.z;
    const float* Wg = (g == 0) ? W0 : (g == 1) ? W1 : (g == 2) ? W2 : W3;
    const int tx = threadIdx.x & 15, ty = threadIdx.x >> 4;
#pragma unroll
    for (int i = 0; i < 4; ++i) {
        float4 v = *(const float4*)(Wg + (size_t)(u0 + ty + i * 16) * K + k0 + tx * 4);
        TT[tx * 4 + 0][ty + i * 16] = v.x;
        TT[tx * 4 + 1][ty + i * 16] = v.y;
        TT[tx * 4 + 2][ty + i * 16] = v.z;
        TT[tx * 4 + 3][ty + i * 16] = v.w;
    }
    __syncthreads();
#pragma unroll
    for (int i = 0; i < 4; ++i) {
        int kl = ty + i * 16;
        float4 o = {TT[kl][tx * 4 + 0], TT[kl][tx * 4 + 1], TT[kl][tx * 4 + 2], TT[kl][tx * 4 + 3]};
        *(float4*)(outT + (size_t)(k0 + kl) * 2048 + g * 512 + u0 + tx * 4) = o;
    }
}

// ---------------------------------------------------------------------------
// combined layer-1 x-path: WcT[k][g*512+u] = sum_e Wi_g[u][e] * W[e][k]
__global__ __launch_bounds__(256) void k_comb(const float* __restrict__ Wi0,
                                              const float* __restrict__ Wi1,
                                              const float* __restrict__ Wi2,
                                              const float* __restrict__ Wi3,
                                              const float* __restrict__ W,
                                              float* __restrict__ WcT) {
    __shared__ float WiS[64][65];   // [u_local][e_local]
    __shared__ float WS[64][65];    // [e_local][k_local]
    const int g  = blockIdx.x >> 3;
    const int u0 = (blockIdx.x & 7) * 64;
    const int k0 = blockIdx.y * 64;
    const float* Wi = (g == 0) ? Wi0 : (g == 1) ? Wi1 : (g == 2) ? Wi2 : Wi3;
    const int tx = threadIdx.x & 15, ty = threadIdx.x >> 4;
    float acc[4][4] = {};   // [ui][kj]
    for (int e0 = 0; e0 < E; e0 += 64) {
#pragma unroll
        for (int i = 0; i < 4; ++i) {
            float4 v = *(const float4*)(Wi + (size_t)(u0 + ty + i * 16) * E + e0 + tx * 4);
            *(float4*)&WiS[ty + i * 16][tx * 4] = v;
        }
#pragma unroll
        for (int i = 0; i < 4; ++i) {
            float4 v = *(const float4*)(W + (size_t)(e0 + ty + i * 16) * H + k0 + tx * 4);
            *(float4*)&WS[ty + i * 16][tx * 4] = v;
        }
        __syncthreads();
#pragma unroll
        for (int el = 0; el < 64; ++el) {
            float uv[4], kv[4];
#pragma unroll
            for (int j = 0; j < 4; ++j) { uv[j] = WiS[ty * 4 + j][el]; kv[j] = WS[el][tx * 4 + j]; }
#pragma unroll
            for (int i2 = 0; i2 < 4; ++i2)
#pragma unroll
                for (int j = 0; j < 4; ++j) acc[i2][j] += uv[i2] * kv[j];
        }
        __syncthreads();
    }
#pragma unroll
    for (int j = 0; j < 4; ++j) {
        float4 o = {acc[0][j], acc[1][j], acc[2][j], acc[3][j]};
        *(float4*)(WcT + (size_t)(k0 + tx * 4 + j) * 2048 + g * 512 + u0 + ty * 4) = o;
    }
}

// ---------------------------------------------------------------------------
// biases (gate-blocked): bias0[g*512+u]=b_g[u]; bias1 += sum_e Wi_g[u][e]*b[e]
__global__ __launch_bounds__(256) void k_bias(const float* __restrict__ WxT,
                                              const float* __restrict__ bi,
                                              const float* __restrict__ bf_,
                                              const float* __restrict__ bg_,
                                              const float* __restrict__ bo_,
                                              const float* __restrict__ bvec,
                                              float* __restrict__ bias0,
                                              float* __restrict__ bias1) {
    int c = blockIdx.x * 256 + threadIdx.x;  // 2048
    int g = c >> 9, u = c & 511;
    const float* bp = (g == 0) ? bi : (g == 1) ? bf_ : (g == 2) ? bg_ : bo_;
    float basev = bp[u];
    float s = 0.f;
    for (int e = 0; e < E; ++e) s += WxT[(size_t)e * 2048 + c] * bvec[e];
    bias0[c] = basev;
    bias1[c] = basev + s;
}

// ---------------------------------------------------------------------------
// pack fp32 [K][2048] into MFMA b-operand fragments, hi/lo bf16 interleaved:
// out[((kb*128 + nb)*2 + h)*512 + lane*8 + j] ;  k=kb*32+(lane>>4)*8+j ; n=nb*16+(lane&15)
__global__ __launch_bounds__(256) void k_pack(const float* __restrict__ Wt,
                                              short* __restrict__ outp) {
    int idx = blockIdx.x * 256 + threadIdx.x;  // K*2048 elements
    int k = idx >> 11, n = idx & 2047;
    float v = Wt[(size_t)k * 2048 + n];
    short hi = f2bf(v);
    short lo = f2bf(v - bf2f(hi));
    int kb = k >> 5, ks = (k >> 3) & 3, j = k & 7;
    int nb = n >> 4, nl = n & 15;
    int lane = ks * 16 + nl;
    size_t base = (((size_t)kb * 128 + nb) * 2) * 512 + (size_t)lane * 8 + j;
    outp[base] = hi;
    outp[base + 512] = lo;
}

// ---------------------------------------------------------------------------
// half-K GEMM sub-loop: kb in [khalf*8, khalf*8+8); A (bf16 hi/lo) x packed B
__device__ __forceinline__ void gemm_h_half(const short* __restrict__ aH,
                                            const short* __restrict__ aL,
                                            const short* __restrict__ Bp,
                                            int ubG, int lane, int ks, int khalf,
                                            f32x4 acc[4]) {
#pragma unroll 4
    for (int kb2 = 0; kb2 < 8; ++kb2) {
        int kb = khalf * 8 + kb2;
        int ko = kb * 32 + ks * 8;
        short8 ahi = *(const short8*)(aH + ko);
        short8 alo = *(const short8*)(aL + ko);
#pragma unroll
        for (int g = 0; g < 4; ++g) {
            const short* bp = Bp + ((((size_t)kb * 4 + g) * 32) + ubG) * 1024 + (size_t)lane * 8;
            short8 bhi = *(const short8*)bp;
            short8 blo = *(const short8*)(bp + 512);
            acc[g] = __builtin_amdgcn_mfma_f32_16x16x32_bf16(ahi, bhi, acc[g], 0, 0, 0);
            acc[g] = __builtin_amdgcn_mfma_f32_16x16x32_bf16(alo, bhi, acc[g], 0, 0, 0);
            acc[g] = __builtin_amdgcn_mfma_f32_16x16x32_bf16(ahi, blo, acc[g], 0, 0, 0);
        }
    }
}

// ---------------------------------------------------------------------------
// staggered phase, K-split x2: 512 threads = 8 waves.
// waves 0-3: K[0:256) of m-subtiles 0-3; waves 4-7: K[256:512) of same tiles.
// Partial sums combined via padded LDS, low-half waves run the epilogue.
__global__ __launch_bounds__(512) void k_phase(int p, const int* __restrict__ X,
        const float* __restrict__ C,
        const short* __restrict__ WxP, const short* __restrict__ WcP,
        const short* __restrict__ WhP,
        const float* __restrict__ bias0g, const float* __restrict__ bias1g,
        short* __restrict__ h0H, short* __restrict__ h0L,
        short* __restrict__ h1H, short* __restrict__ h1L,
        float* __restrict__ c0, float* __restrict__ c1) {
    const int panel = blockIdx.y;
    if (panel == 0 && p >= S) return;
    if (panel == 1 && p == 0) return;
    const int tid   = threadIdx.x;
    const int wave  = tid >> 6, lane = tid & 63;
    const int khalf = wave >> 2, wsub = wave & 3;
    const int lrow  = lane & 15, ks = lane >> 4;
    const int msup  = blockIdx.x & 3;     // 4 m-supertiles of 64 rows
    const int ubG   = blockIdx.x >> 2;    // 32 u-blocks of 16 units
    const int row   = msup * 64 + wsub * 16 + lrow;
    const int u     = ubG * 16 + lrow;

    __shared__ float red[4][64][17];      // [wsub][lane][16 + pad]

    f32x4 acc[4];
#pragma unroll
    for (int g = 0; g < 4; ++g) acc[g] = (f32x4){0.f, 0.f, 0.f, 0.f};

    if (panel == 0) {
        // x-part: embedding K=256 -> kb [khalf*4, khalf*4+4)
        const int tok = X[row * S + p];
        const float* crow = C + (size_t)tok * E;
#pragma unroll
        for (int kb2 = 0; kb2 < 4; ++kb2) {
            int kb = khalf * 4 + kb2;
            int ko = kb * 32 + ks * 8;
            float4 v0 = *(const float4*)(crow + ko);
            float4 v1 = *(const float4*)(crow + ko + 4);
            float v[8] = {v0.x, v0.y, v0.z, v0.w, v1.x, v1.y, v1.z, v1.w};
            short8 ahi, alo;
#pragma unroll
            for (int j = 0; j < 8; ++j) {
                short hj = f2bf(v[j]);
                ahi[j] = hj;
                alo[j] = f2bf(v[j] - bf2f(hj));
            }
#pragma unroll
            for (int g = 0; g < 4; ++g) {
                const short* bp = WxP + ((((size_t)kb * 4 + g) * 32) + ubG) * 1024 + (size_t)lane * 8;
                short8 bhi = *(const short8*)bp;
                short8 blo = *(const short8*)(bp + 512);
                acc[g] = __builtin_amdgcn_mfma_f32_16x16x32_bf16(ahi, bhi, acc[g], 0, 0, 0);
                acc[g] = __builtin_amdgcn_mfma_f32_16x16x32_bf16(alo, bhi, acc[g], 0, 0, 0);
                acc[g] = __builtin_amdgcn_mfma_f32_16x16x32_bf16(ahi, blo, acc[g], 0, 0, 0);
            }
        }
        // h-part: h0 parity (p+1)&1, K=512 -> kb [khalf*8, +8)
        size_t off = (size_t)((p + 1) & 1) * B * H + (size_t)row * H;
        gemm_h_half(h0H + off, h0L + off, WhP, ubG, lane, ks, khalf, acc);
    } else {
        const int q = p - 1;
        size_t offx = (size_t)(q & 1) * B * H + (size_t)row * H;          // x = h0[q]
        gemm_h_half(h0H + offx, h0L + offx, WcP, ubG, lane, ks, khalf, acc);
        size_t offh = (size_t)((q + 1) & 1) * B * H + (size_t)row * H;    // h1[q-1]
        gemm_h_half(h1H + offh, h1L + offh, WhP, ubG, lane, ks, khalf, acc);
    }

    // combine K-halves: high half deposits, low half reduces + epilogue
    if (khalf == 1) {
#pragma unroll
        for (int g = 0; g < 4; ++g)
#pragma unroll
            for (int r = 0; r < 4; ++r) red[wsub][lane][g * 4 + r] = acc[g][r];
    }
    __syncthreads();
    if (khalf == 1) return;

#pragma unroll
    for (int g = 0; g < 4; ++g)
#pragma unroll
        for (int r = 0; r < 4; ++r) acc[g][r] += red[wsub][lane][g * 4 + r];

    short* dH; short* dL; float* cb;
    if (panel == 0) { size_t off = (size_t)(p & 1) * B * H; dH = h0H + off; dL = h0L + off; cb = c0; }
    else            { size_t off = (size_t)((p - 1) & 1) * B * H; dH = h1H + off; dL = h1L + off; cb = c1; }
    const float* bias = panel ? bias1g : bias0g;
    const float bI = bias[u], bF = bias[512 + u], bG = bias[1024 + u], bO = bias[1536 + u];
    const int rbase = msup * 64 + wsub * 16 + ks * 4;
#pragma unroll
    for (int r = 0; r < 4; ++r) {
        size_t ix = (size_t)(rbase + r) * H + u;
        float pi = acc[0][r] + bI;
        float pf = acc[1][r] + bF;
        float pg = acc[2][r] + bG;
        float po = acc[3][r] + bO;
        float iv = 1.f / (1.f + expf(-pi));
        float fv = 1.f / (1.f + expf(-pf));
        float gv = tanhf(pg);
        float ov = 1.f / (1.f + expf(-po));
        float cn = fv * cb[ix] + iv * gv;
        float hn = ov * tanhf(cn);
        cb[ix] = cn;
        short hh = f2bf(hn);
        dH[ix] = hh;
        dL[ix] = f2bf(hn - bf2f(hh));
    }
}

// ---------------------------------------------------------------------------
// classifier with LDS-staged Wf: block stages 128n x 64k fp32 -> bf16 into a
// XOR-swizzled LDS tile (read coalesced, converted once), waves consume
// fragments via ds_read_b128. Wf is read from HBM exactly once.
__global__ __launch_bounds__(1024) void k_cls(const short* __restrict__ hH,
                                              const short* __restrict__ hL,
                                              const float* __restrict__ Wf,
                                              const float* __restrict__ bfin,
                                              float* __restrict__ out) {
    const int tid  = threadIdx.x;
    const int wave = tid >> 6, lane = tid & 63;
    const int lrow = lane & 15, ks = lane >> 4;
    const int n0 = blockIdx.x * 128;
    const int m0 = wave * 16;

    __shared__ short BT[128 * 64];   // 16 KB, swizzled: byte ^= (row&7)<<4

    f32x4 acc[8];
#pragma unroll
    for (int nf = 0; nf < 8; ++nf) acc[nf] = (f32x4){0.f, 0.f, 0.f, 0.f};
    const short* aH = hH + (size_t)(m0 + lrow) * H;
    const short* aL = hL + (size_t)(m0 + lrow) * H;

    const int rowl = tid >> 3;          // 128 rows, 8 threads/row
    const int kcol = (tid & 7) * 8;     // 8 k each

    for (int kc = 0; kc < 8; ++kc) {    // 8 chunks of 64 k
        // stage chunk: coalesced fp32 read, cvt to bf16, swizzled LDS store
        {
            const float* wr = Wf + (size_t)(n0 + rowl) * H + kc * 64 + kcol;
            float4 v0 = *(const float4*)wr;
            float4 v1 = *(const float4*)(wr + 4);
            short8 bw;
            bw[0] = f2bf(v0.x); bw[1] = f2bf(v0.y); bw[2] = f2bf(v0.z); bw[3] = f2bf(v0.w);
            bw[4] = f2bf(v1.x); bw[5] = f2bf(v1.y); bw[6] = f2bf(v1.z); bw[7] = f2bf(v1.w);
            int byteoff = (rowl * 128 + kcol * 2) ^ ((rowl & 7) << 4);
            *(short8*)((char*)BT + byteoff) = bw;
        }
        __syncthreads();
#pragma unroll
        for (int kbi = 0; kbi < 2; ++kbi) {
            int ko = kc * 64 + kbi * 32 + ks * 8;
            short8 ahi = *(const short8*)(aH + ko);
            short8 alo = *(const short8*)(aL + ko);
#pragma unroll
            for (int nf = 0; nf < 8; ++nf) {
                int nl = nf * 16 + lrow;
                int byte = (nl * 128 + (kbi * 32 + ks * 8) * 2) ^ ((nl & 7) << 4);
                short8 b = *(const short8*)((const char*)BT + byte);
                acc[nf] = __builtin_amdgcn_mfma_f32_16x16x32_bf16(ahi, b, acc[nf], 0, 0, 0);
                acc[nf] = __builtin_amdgcn_mfma_f32_16x16x32_bf16(alo, b, acc[nf], 0, 0, 0);
            }
        }
        __syncthreads();
    }

#pragma unroll
    for (int nf = 0; nf < 8; ++nf) {
        int n = n0 + nf * 16 + lrow;
        float bias = bfin[n];
#pragma unroll
        for (int r = 0; r < 4; ++r) {
            int brow = m0 + ks * 4 + r;
            out[(size_t)brow * NC + n] = acc[nf][r] + bias;
        }
    }
}

// ---------------------------------------------------------------------------
extern "C" void kernel_launch(void* const* d_in, const int* in_sizes, int n_in,
                              void* d_out, int out_size, void* d_ws, size_t ws_size,
                              hipStream_t stream) {
    const int*   X    = (const int*)d_in[0];
    const float* C    = (const float*)d_in[1];
    const float* Wii  = (const float*)d_in[2];
    const float* Whi  = (const float*)d_in[3];
    const float* bi   = (const float*)d_in[4];
    const float* Wif  = (const float*)d_in[5];
    const float* Whf  = (const float*)d_in[6];
    const float* bf   = (const float*)d_in[7];
    const float* Wig  = (const float*)d_in[8];
    const float* Whg  = (const float*)d_in[9];
    const float* bg   = (const float*)d_in[10];
    const float* Wio  = (const float*)d_in[11];
    const float* Who  = (const float*)d_in[12];
    const float* bo   = (const float*)d_in[13];
    const float* W    = (const float*)d_in[14];
    const float* bvec = (const float*)d_in[15];
    const float* Wf   = (const float*)d_in[16];
    const float* bfin = (const float*)d_in[17];
    float* out = (float*)d_out;
    char* base = (char*)d_ws;

    // ws layout (bytes), total ~24.1 MB
    float* WhT  = (float*)(base + 0);          // 512*2048*4 = 4,194,304
    float* WxT  = (float*)(base + 4194304);    // 256*2048*4 = 2,097,152
    float* WcT  = (float*)(base + 6291456);    // 4,194,304
    short* WhP  = (short*)(base + 10485760);   // 4,194,304
    short* WxP  = (short*)(base + 14680064);   // 2,097,152
    short* WcP  = (short*)(base + 16777216);   // 4,194,304
    float* bias0 = (float*)(base + 20971520);  // 8192
    float* bias1 = (float*)(base + 20979712);  // 8192
    short* h0H  = (short*)(base + 20987904);   // [2][256][512] bf16 = 524,288 each
    short* h0L  = (short*)(base + 21512192);
    short* h1H  = (short*)(base + 22036480);
    short* h1L  = (short*)(base + 22560768);
    float* c0   = (float*)(base + 23085056);   // 524,288
    float* c1   = (float*)(base + 23609344);   // 524,288

    // zero h-splits (both parities) + cell states: 6*524288 B = 196608 float4
    k_zero<<<768, 256, 0, stream>>>((float4*)(base + 20987904), 196608);

    k_trans<<<dim3(8, 8, 4), 256, 0, stream>>>(Whi, Whf, Whg, Who, H, WhT);
    k_trans<<<dim3(8, 4, 4), 256, 0, stream>>>(Wii, Wif, Wig, Wio, E, WxT);
    k_comb<<<dim3(32, 8), 256, 0, stream>>>(Wii, Wif, Wig, Wio, W, WcT);
    k_pack<<<4096, 256, 0, stream>>>(WhT, WhP);
    k_pack<<<2048, 256, 0, stream>>>(WxT, WxP);
    k_pack<<<4096, 256, 0, stream>>>(WcT, WcP);
    k_bias<<<8, 256, 0, stream>>>(WxT, bi, bf, bg, bo, bvec, bias0, bias1);

    for (int p = 0; p <= S; ++p)
        k_phase<<<dim3(128, 2), 512, 0, stream>>>(p, X, C, WxP, WcP, WhP, bias0, bias1,
                                                  h0H, h0L, h1H, h1L, c0, c1);

    // final h1 (t=63) is in parity 1
    k_cls<<<250, 1024, 0, stream>>>(h1H + (size_t)B * H, h1L + (size_t)B * H, Wf, bfin, out);
}